// Round 6
// baseline (210.191 us; speedup 1.0000x reference)
//
#include <hip/hip_runtime.h>
#include <hip/hip_bf16.h>
#include <math.h>

#define BB 8
#define CC 64
#define HH 128
#define WW 128
#define HO 64
#define WO 128
#define OC 64
#define HW (HH * WW)
#define NPM (BB * 9 * HO * WO)

typedef __attribute__((ext_vector_type(8))) short short8;
typedef __attribute__((ext_vector_type(4))) float floatx4;
typedef float float2v __attribute__((ext_vector_type(2)));
typedef float float2a __attribute__((ext_vector_type(2), aligned(4)));  // 8B load, 4B align ok

union BfBits { __hip_bfloat16 h; short s; };

// ---------------------------------------------------------------------------
// Prep A: w_off/w_msk -> w3[c][256] fp32 contiguous (co*9+k).
// ---------------------------------------------------------------------------
__global__ __launch_bounds__(256) void make_w3(
    const float* __restrict__ w_off, const float* __restrict__ w_msk,
    float* __restrict__ w3)
{
    int i = blockIdx.x * 256 + threadIdx.x;   // 15552 = 27*64*9
    if (i >= 27 * CC * 9) return;
    int kk = i % 9;
    int c  = (i / 9) % CC;
    int co = i / (9 * CC);
    float v = (co < 18) ? w_off[(co * CC + c) * 9 + kk]
                        : w_msk[((co - 18) * CC + c) * 9 + kk];
    w3[c * 256 + co * 9 + kk] = v;
}

// ---------------------------------------------------------------------------
// Prep B: w_conv (o,c,k) fp32 -> W2[k][o][c] bf16 (MFMA A-operand layout).
// ---------------------------------------------------------------------------
__global__ __launch_bounds__(256) void make_w2(
    const float* __restrict__ w_conv, __hip_bfloat16* __restrict__ W2)
{
    int i = blockIdx.x * 256 + threadIdx.x;   // 36864 exactly
    int k = i % 9;
    int c = (i / 9) % CC;
    int o = i / (CC * 9);
    W2[((size_t)k * OC + o) * CC + c] = __float2bfloat16(w_conv[i]);
}

// ---------------------------------------------------------------------------
// Kernel 1: offset+mask conv. launch_bounds(256,3): VGPR cap ~170 so the
// one-channel-ahead patch loads (xq) stay IN FLIGHT instead of being sunk
// by occupancy-targeted regalloc (R5: default cap ~64 VGPR serialized them).
// ---------------------------------------------------------------------------
__global__ __launch_bounds__(256, 3) void om_conv(
    const float* __restrict__ x, const float* __restrict__ w3,
    const float* __restrict__ b_off, const float* __restrict__ b_msk,
    float2v* __restrict__ pypx, float* __restrict__ m_out)
{
    __shared__ float red[4][64][29];   // pad 29 -> conflict-free

    int tid = threadIdx.x;
    int lane = tid & 63;
    int chunk = __builtin_amdgcn_readfirstlane(tid >> 6);

    int bx = blockIdx.x;               // 1024 blocks
    int b = bx & 7;                    // XCD-local batch
    int rest = bx >> 3;                // 128 = 64 h * 2 w-halves
    int h = rest >> 1;
    int w = (rest & 1) * 64 + lane;
    int h2 = 2 * h - 1;
    int wm1 = w - 1;

    int idx9[9];
    float msk9[9];
#pragma unroll
    for (int ky = 0; ky < 3; ++ky) {
        int hy = h2 + ky;
        int hyc = min(max(hy, 0), HH - 1);
        float my = ((unsigned)hy < (unsigned)HH) ? 1.0f : 0.0f;
#pragma unroll
        for (int kx = 0; kx < 3; ++kx) {
            int xw = wm1 + kx;
            int xwc = min(max(xw, 0), WW - 1);
            float mx = ((unsigned)xw < (unsigned)WW) ? 1.0f : 0.0f;
            idx9[ky * 3 + kx] = hyc * WW + xwc;
            msk9[ky * 3 + kx] = my * mx;
        }
    }

    float acc[27];
#pragma unroll
    for (int co = 0; co < 27; ++co) acc[co] = 0.0f;

    const float* xb = x + (size_t)b * (CC * HW) + (size_t)chunk * 16 * HW;

    float xp[9], xq[9];
#pragma unroll
    for (int k = 0; k < 9; ++k) xp[k] = xb[idx9[k]] * msk9[k];

    for (int ci = 0; ci < 16; ++ci) {
        if (ci < 15) {
            const float* xc = xb + (ci + 1) * HW;
#pragma unroll
            for (int k = 0; k < 9; ++k) xq[k] = xc[idx9[k]];
        }
        int c = chunk * 16 + ci;
        const float* wc = w3 + c * 256;     // wave-uniform -> s_load
#pragma unroll
        for (int co = 0; co < 27; ++co) {
            float s = acc[co];
#pragma unroll
            for (int k = 0; k < 9; ++k) s = fmaf(wc[co * 9 + k], xp[k], s);
            acc[co] = s;
        }
#pragma unroll
        for (int k = 0; k < 9; ++k) xp[k] = xq[k] * msk9[k];
    }

#pragma unroll
    for (int co = 0; co < 27; ++co) red[chunk][lane][co] = acc[co];
    __syncthreads();

    if (tid < 64) {
        float s[27];
#pragma unroll
        for (int co = 0; co < 27; ++co)
            s[co] = red[0][lane][co] + red[1][lane][co]
                  + red[2][lane][co] + red[3][lane][co];
        int base = ((b * 9) * HO + h) * WO + w;
#pragma unroll
        for (int k = 0; k < 9; ++k) {
            float2v pp;
            pp.x = s[2 * k] + b_off[2 * k] + (float)(k / 3) + (float)h2;
            pp.y = s[2 * k + 1] + b_off[2 * k + 1] + (float)(k % 3) + (float)wm1;
            pypx[base + k * HO * WO] = pp;
            m_out[base + k * HO * WO] =
                1.0f / (1.0f + __expf(-(s[18 + k] + b_msk[k])));
        }
    }
}

// ---------------------------------------------------------------------------
// Kernel 2: deformable sampling + MFMA matvec. launch_bounds(256,3) so the
// 16 paired-corner gathers (32 VGPRs of data) genuinely stay in flight.
// All 9 taps' (py,px,mask) preloaded to registers; tap loop fully unrolled.
// ---------------------------------------------------------------------------
__global__ __launch_bounds__(256, 3) void dconv_mfma(
    const float* __restrict__ x,
    const float2v* __restrict__ pypx, const float* __restrict__ m_in,
    const __hip_bfloat16* __restrict__ W2,
    float* __restrict__ out)
{
    __shared__ __align__(16) __hip_bfloat16 S[2][32][64];  // 8 KB

    int tid = threadIdx.x;
    int lane = tid & 63;
    int wv = tid >> 6;

    int bx = blockIdx.x;               // 2048 blocks
    int b = bx & 7;
    int rest = bx >> 3;                // 256 = 64 h * 4 w-quarters
    int h = rest >> 2;
    int w0 = (rest & 3) * 32;

    int gpos = tid & 31;
    int cg = tid >> 5;                 // 0..7 -> channels cg*8..+8
    const int m16 = lane & 15;
    const int q = lane >> 4;

    floatx4 acc[2];
    acc[0] = (floatx4){0.f, 0.f, 0.f, 0.f};
    acc[1] = (floatx4){0.f, 0.f, 0.f, 0.f};

    const float* xg = x + (size_t)b * (CC * HW) + (size_t)cg * 8 * HW;
    int pidx = ((b * 9) * HO + h) * WO + w0 + gpos;

    // preload all 9 taps' coords+mask (27 VGPRs, removes per-tap pypx wait)
    float2v pp9[9];
    float mk9[9];
#pragma unroll
    for (int k = 0; k < 9; ++k) {
        pp9[k] = pypx[pidx + k * (HO * WO)];
        mk9[k] = m_in[pidx + k * (HO * WO)];
    }

    float2a P[8], Q[8];
    float cxA, cyA, cxB, cyB;

    auto issue = [&](float2v pp, float mk) {
        float py = pp.x, px = pp.y;
        float y0f = floorf(py), x0f = floorf(px);
        float dy = py - y0f, dx = px - x0f;
        int y0 = (int)y0f, x0 = (int)x0f;
        int y1 = y0 + 1, x1 = x0 + 1;
        bool vy0 = (unsigned)y0 < (unsigned)HH;
        bool vy1 = (unsigned)y1 < (unsigned)HH;
        bool vx0 = (unsigned)x0 < (unsigned)WW;
        bool vx1 = (unsigned)x1 < (unsigned)WW;
        float w00 = (1.0f - dy) * (1.0f - dx) * ((vy0 && vx0) ? mk : 0.0f);
        float w01 = (1.0f - dy) * dx          * ((vy0 && vx1) ? mk : 0.0f);
        float w10 = dy * (1.0f - dx)          * ((vy1 && vx0) ? mk : 0.0f);
        float w11 = dy * dx                   * ((vy1 && vx1) ? mk : 0.0f);
        int xbase = min(max(x0, 0), WW - 2);
        bool s0 = x0 > xbase;
        bool s1 = x1 > xbase;
        cxA = (s0 ? 0.f : w00) + (s1 ? 0.f : w01);
        cyA = (s0 ? w00 : 0.f) + (s1 ? w01 : 0.f);
        cxB = (s0 ? 0.f : w10) + (s1 ? 0.f : w11);
        cyB = (s0 ? w10 : 0.f) + (s1 ? w11 : 0.f);
        int yc0 = min(max(y0, 0), HH - 1);
        int yc1 = min(max(y1, 0), HH - 1);
        int r0 = yc0 * WW + xbase, r1 = yc1 * WW + xbase;
#pragma unroll
        for (int j = 0; j < 8; ++j) {
            P[j] = *(const float2a*)(xg + (size_t)j * HW + r0);
            Q[j] = *(const float2a*)(xg + (size_t)j * HW + r1);
        }
    };

    auto combine_store = [&](int buf) {
        short8 sv;
#pragma unroll
        for (int j = 0; j < 8; ++j) {
            float gv = cxA * P[j].x + cyA * P[j].y
                     + cxB * Q[j].x + cyB * Q[j].y;
            BfBits u; u.h = __float2bfloat16(gv);
            sv[j] = u.s;
        }
        *(short8*)&S[buf][gpos][(cg ^ (gpos & 7)) * 8] = sv;
    };

    issue(pp9[0], mk9[0]);
    combine_store(0);

#pragma unroll
    for (int k = 0; k < 9; ++k) {
        __syncthreads();               // S[k&1] ready for all waves
        if (k < 8) issue(pp9[k + 1], mk9[k + 1]);   // in flight during MFMA
        {
            const __hip_bfloat16* wk =
                W2 + ((size_t)(k * OC) + wv * 16 + m16) * CC + q * 8;
            int buf = k & 1;
#pragma unroll
            for (int s = 0; s < 2; ++s) {
                short8 af = *(const short8*)(wk + s * 32);
                int cb = ((q + 4 * s) ^ (m16 & 7)) * 8;
                short8 bf0 = *(const short8*)&S[buf][m16][cb];
                short8 bf1 = *(const short8*)&S[buf][16 + m16][cb];
                acc[0] = __builtin_amdgcn_mfma_f32_16x16x32_bf16(af, bf0, acc[0], 0, 0, 0);
                acc[1] = __builtin_amdgcn_mfma_f32_16x16x32_bf16(af, bf1, acc[1], 0, 0, 0);
            }
        }
        if (k < 8) combine_store((k + 1) & 1);
    }

    // epilogue: C/D col=lane&15 (pos), row=(lane>>4)*4+reg (o)
#pragma unroll
    for (int nt = 0; nt < 2; ++nt) {
#pragma unroll
        for (int r = 0; r < 4; ++r) {
            int o = wv * 16 + q * 4 + r;
            out[(((size_t)b * OC + o) * HO + h) * WO + w0 + nt * 16 + m16]
                = acc[nt][r];
        }
    }
}

// ---------------------------------------------------------------------------
extern "C" void kernel_launch(void* const* d_in, const int* in_sizes, int n_in,
                              void* d_out, int out_size, void* d_ws, size_t ws_size,
                              hipStream_t stream)
{
    const float* x      = (const float*)d_in[0];
    const float* w_off  = (const float*)d_in[1];
    const float* b_off  = (const float*)d_in[2];
    const float* w_msk  = (const float*)d_in[3];
    const float* b_msk  = (const float*)d_in[4];
    const float* w_conv = (const float*)d_in[5];
    float* out = (float*)d_out;

    float2v* pypx = (float2v*)d_ws;                       // NPM float2
    float* m  = (float*)(pypx + NPM);                     // NPM floats
    __hip_bfloat16* W2 = (__hip_bfloat16*)(m + NPM);      // 36864 bf16
    float* w3 = (float*)(W2 + 9 * OC * CC);               // 16384 floats

    make_w3<<<dim3(61), dim3(256), 0, stream>>>(w_off, w_msk, w3);
    make_w2<<<dim3(144), dim3(256), 0, stream>>>(w_conv, W2);
    om_conv<<<dim3(1024), dim3(256), 0, stream>>>(x, w3, b_off, b_msk, pypx, m);
    dconv_mfma<<<dim3(2048), dim3(256), 0, stream>>>(x, pypx, m, W2, out);
}